// Round 10
// baseline (137.721 us; speedup 1.0000x reference)
//
#include <hip/hip_runtime.h>
#include <hip/hip_bf16.h>
#include <cstdint>
#include <math.h>

#define B_DIM 32
#define T_DIM 1000
#define D_DIM 768
#define V_DIM 31
#define L_DIM 200
#define S_DIM 401      // 2L+1 CTC states
#define SP 7           // states per lane (64*7 = 448 >= 401)
#define S_PAD 448
#define VSTRIDE 32     // padded prob-row stride: 32 floats = 128 B

typedef __bf16 bf16x8 __attribute__((ext_vector_type(8)));
typedef float  f32x16 __attribute__((ext_vector_type(16)));

// Wave-wide shift-up-by-1 via DPP WAVE_SHR1 (0x138): pure VALU. Lane 0 -> 0.
__device__ __forceinline__ float shup1_f(float x) {
    int r = __builtin_amdgcn_update_dpp(0, __float_as_int(x), 0x138, 0xF, 0xF, true);
    return __int_as_float(r);
}
__device__ __forceinline__ int shup1_i(int x) {
    return __builtin_amdgcn_update_dpp(0, x, 0x138, 0xF, 0xF, true);
}

// ---------------------------------------------------------------------------
// Kernel 1: logits = pred @ W^T + b via MFMA bf16, probs = softmax -> ws.
// (Unchanged from round 8: ~29 us.)
// ---------------------------------------------------------------------------
__global__ __launch_bounds__(256) void head_softmax_kernel(
    const float* __restrict__ pred,
    const float* __restrict__ W,
    const float* __restrict__ bias,
    float* __restrict__ probs)
{
    __shared__ float red[3][64][16];   // waves 1..3 partial C tiles (12 KB)
    __shared__ float sm2[32][33];      // transpose pad 33 -> conflict-free
    const int tid  = threadIdx.x;
    const int lane = tid & 63;
    const int w    = __builtin_amdgcn_readfirstlane(tid >> 6);  // K segment
    const int col  = lane & 31;
    const int h    = lane >> 5;
    const int row  = blockIdx.x * 32 + col;     // grid = 1000 exactly
    const int vc   = (col < V_DIM) ? col : (V_DIM - 1);  // clamp pad col

    const float* pA = pred + (size_t)row * D_DIM + w * 192 + 8 * h;
    const float* pB = W + (size_t)vc * D_DIM + w * 192 + 8 * h;

    f32x16 acc;
#pragma unroll
    for (int i = 0; i < 16; ++i) acc[i] = 0.f;

#pragma unroll
    for (int kt = 0; kt < 12; ++kt) {
        const float4 a0 = *reinterpret_cast<const float4*>(pA + kt * 16);
        const float4 a1 = *reinterpret_cast<const float4*>(pA + kt * 16 + 4);
        const float4 b0 = *reinterpret_cast<const float4*>(pB + kt * 16);
        const float4 b1 = *reinterpret_cast<const float4*>(pB + kt * 16 + 4);
        bf16x8 af, bfr;
        af[0] = (__bf16)a0.x; af[1] = (__bf16)a0.y;
        af[2] = (__bf16)a0.z; af[3] = (__bf16)a0.w;
        af[4] = (__bf16)a1.x; af[5] = (__bf16)a1.y;
        af[6] = (__bf16)a1.z; af[7] = (__bf16)a1.w;
        bfr[0] = (__bf16)b0.x; bfr[1] = (__bf16)b0.y;
        bfr[2] = (__bf16)b0.z; bfr[3] = (__bf16)b0.w;
        bfr[4] = (__bf16)b1.x; bfr[5] = (__bf16)b1.y;
        bfr[6] = (__bf16)b1.z; bfr[7] = (__bf16)b1.w;
        acc = __builtin_amdgcn_mfma_f32_32x32x16_bf16(af, bfr, acc, 0, 0, 0);
    }

    if (w > 0) {
#pragma unroll
        for (int q = 0; q < 4; ++q)
            *reinterpret_cast<float4*>(&red[w - 1][lane][q * 4]) =
                make_float4(acc[q * 4], acc[q * 4 + 1], acc[q * 4 + 2], acc[q * 4 + 3]);
    }
    __syncthreads();
    if (w == 0) {
#pragma unroll
        for (int i = 0; i < 16; ++i)
            acc[i] += red[0][lane][i] + red[1][lane][i] + red[2][lane][i];
#pragma unroll
        for (int r = 0; r < 16; ++r) {
            const int rl = (r & 3) + 8 * (r >> 2) + 4 * h;
            sm2[rl][col] = acc[r];
        }
        if (lane < 32) {
            float lg[V_DIM];
            float m = -1e30f;
#pragma unroll
            for (int v = 0; v < V_DIM; ++v) {
                lg[v] = sm2[lane][v] + bias[v];
                m = fmaxf(m, lg[v]);
            }
            float e[32];
            float s = 0.f;
#pragma unroll
            for (int v = 0; v < V_DIM; ++v) { e[v] = __expf(lg[v] - m); s += e[v]; }
            const float inv = 1.0f / s;
#pragma unroll
            for (int v = 0; v < V_DIM; ++v) e[v] *= inv;
            e[31] = 0.f;
            float* op = probs + (size_t)(blockIdx.x * 32 + lane) * VSTRIDE;
#pragma unroll
            for (int q = 0; q < 8; ++q)
                *reinterpret_cast<float4*>(op + q * 4) =
                    *reinterpret_cast<float4*>(&e[q * 4]);
        }
    }
}

// ---------------------------------------------------------------------------
// Kernel 2: CTC forward recursion, linear domain, pow2 renorm every 2 steps.
// DMA staging into a 3-chunk LDS ring; 2-step read-ahead via a 4-buffer
// register rotation (B0..B3, static indexing, no copies). ds_read latency
// (~120 cyc) hides under ~2 steps of VALU. vmcnt stays counted; the
// boundary vmcnt(8) is satisfied ~3000 cyc early at steady state.
// ---------------------------------------------------------------------------
__global__ __launch_bounds__(64, 1) void ctc_alpha_kernel(
    const float* __restrict__ probs,
    const int* __restrict__ targets,
    const int* __restrict__ in_lens,
    const int* __restrict__ tgt_lens,
    float* __restrict__ out_nll)
{
    __shared__ float lbuf[3][16][VSTRIDE];   // 6 KB ring (3 chunks x 16 rows)
    __shared__ float sal[S_PAD];

    const int b    = blockIdx.x;
    const int lane = threadIdx.x;
    const int Tin  = in_lens[b];
    const int tl   = tgt_lens[b];
    const int* tgt = targets + b * L_DIM;
    const float* __restrict__ prow = probs + (size_t)b * T_DIM * VSTRIDE;

    int   eoff[SP];
    float m2[SP];
#pragma unroll
    for (int i = 0; i < SP; ++i) {
        const int s = lane * SP + i;
        int e = 0;
        float mm = 0.f;
        if (s < S_DIM && (s & 1)) {
            const int k = (s - 1) >> 1;
            const int lab = tgt[k];
            e = lab;
            if (s >= 3 && lab != tgt[k - 1]) mm = 1.f;
        }
        eoff[i] = e;
        m2[i]   = mm;
    }

    // t=0 init
    float a[SP];
#pragma unroll
    for (int i = 0; i < SP; ++i) a[i] = 0.f;
    if (lane == 0) {
        a[0] = prow[0];
        a[1] = prow[eoff[1]];
    }
    int   z2 = 0;
    float f  = (lane == 0) ? 0.f : 1.0f;

    auto ISSUE = [&](int buf, int tbase) {
#pragma unroll
        for (int i = 0; i < 8; ++i) {
            int rowb = tbase + 2 * i;
            if (rowb > T_DIM - 2) rowb = T_DIM - 2;   // clamp, stays in-bounds
            const float* src = prow + (size_t)rowb * VSTRIDE + lane;
            float* dst = &lbuf[buf][2 * i][0];        // wave-uniform base
            __builtin_amdgcn_global_load_lds(
                (const __attribute__((address_space(1))) void*)src,
                (__attribute__((address_space(3))) void*)dst, 4, 0, 0);
        }
    };

    float B0[SP], B1[SP], B2[SP], B3[SP];
    auto RD = [&](const float* base, int row, float (&dst)[SP]) {
#pragma unroll
        for (int i = 0; i < SP; ++i) dst[i] = base[row * VSTRIDE + eoff[i]];
    };

    auto STEP = [&](const float (&pp)[SP]) {
        const float a6  = shup1_f(a[SP - 1]);   // DPP: lane0 -> 0
        const float a5  = shup1_f(a[SP - 2]);
        const float am1 = a6 * f;
        const float am2 = a5 * f;
        float nw[SP];
        nw[0] = (a[0] + am1  + m2[0] * am2) * pp[0];
        nw[1] = (a[1] + a[0] + m2[1] * am1) * pp[1];
#pragma unroll
        for (int i = 2; i < SP; ++i)
            nw[i] = (a[i] + a[i - 1] + m2[i] * a[i - 2]) * pp[i];
#pragma unroll
        for (int i = 0; i < SP; ++i) a[i] = nw[i];
    };

    auto RENORM = [&]() {
        const float mx = fmaxf(fmaxf(fmaxf(a[0], a[1]), fmaxf(a[2], a[3])),
                               fmaxf(fmaxf(a[4], a[5]), a[6]));
        int e;
        (void)frexpf(mx, &e);                    // mx==0 -> e=0
        const int zc = z2 + e;
        const int zp = shup1_i(zc);
        z2 = (mx > 0.f) ? zc : ((lane == 0) ? zc : zp);
#pragma unroll
        for (int i = 0; i < SP; ++i) a[i] = ldexpf(a[i], -e);
        int dz = zp - z2;
        if (dz > 126) dz = 126;
        if (dz < -126) dz = -126;
        f = (lane == 0) ? 0.f : ldexpf(1.0f, dz);
    };

    ISSUE(0, 1);            // chunk 0: rows 1..16
    ISSUE(1, 17);           // chunk 1: rows 17..32
    asm volatile("s_waitcnt vmcnt(8)" ::: "memory");  // chunk 0 landed
    {
        const float* Lb = &lbuf[0][0][0];
        RD(Lb, 0, B0);
        RD(Lb, 1, B1);
    }

    int tb = 1;
    int cur = 0;
    while (tb + 16 <= Tin) {
        const float* Lb = &lbuf[cur][0][0];
        const int nx = (cur + 1 == 3) ? 0 : cur + 1;
        const int n2 = (nx + 1 == 3) ? 0 : nx + 1;
        RD(Lb,  2, B2); STEP(B0);
        RD(Lb,  3, B3); STEP(B1); RENORM();
        RD(Lb,  4, B0); STEP(B2);
        RD(Lb,  5, B1); STEP(B3); RENORM();
        RD(Lb,  6, B2); STEP(B0);
        RD(Lb,  7, B3); STEP(B1); RENORM();
        RD(Lb,  8, B0); STEP(B2);
        RD(Lb,  9, B1); STEP(B3); RENORM();
        RD(Lb, 10, B2); STEP(B0);
        RD(Lb, 11, B3); STEP(B1); RENORM();
        RD(Lb, 12, B0); STEP(B2);
        RD(Lb, 13, B1); STEP(B3); RENORM();
        RD(Lb, 14, B2); STEP(B0);
        RD(Lb, 15, B3); STEP(B1); RENORM();
        ISSUE(n2, tb + 32);                                // refill oldest buffer
        asm volatile("s_waitcnt vmcnt(8)" ::: "memory");   // next chunk landed
        {
            const float* Ln = &lbuf[nx][0][0];
            RD(Ln, 0, B0); STEP(B2);                       // step 14 (row 14)
            RD(Ln, 1, B1); STEP(B3); RENORM();             // step 15 (row 15)
        }
        tb += 16;
        cur = nx;
    }

    // tail: rem <= 15 steps in chunk cur (landed); B0,B1 = rows 0,1
    const int rem = Tin - tb;
    {
        const float* Lb = &lbuf[cur][0][0];
        if (rem >  0) { RD(Lb,  2, B2); STEP(B0); }
        if (rem >  1) { RD(Lb,  3, B3); STEP(B1); RENORM(); }
        if (rem >  2) { RD(Lb,  4, B0); STEP(B2); }
        if (rem >  3) { RD(Lb,  5, B1); STEP(B3); RENORM(); }
        if (rem >  4) { RD(Lb,  6, B2); STEP(B0); }
        if (rem >  5) { RD(Lb,  7, B3); STEP(B1); RENORM(); }
        if (rem >  6) { RD(Lb,  8, B0); STEP(B2); }
        if (rem >  7) { RD(Lb,  9, B1); STEP(B3); RENORM(); }
        if (rem >  8) { RD(Lb, 10, B2); STEP(B0); }
        if (rem >  9) { RD(Lb, 11, B3); STEP(B1); RENORM(); }
        if (rem > 10) { RD(Lb, 12, B0); STEP(B2); }
        if (rem > 11) { RD(Lb, 13, B1); STEP(B3); RENORM(); }
        if (rem > 12) { RD(Lb, 14, B2); STEP(B0); }
        if (rem > 13) { RD(Lb, 15, B3); STEP(B1); RENORM(); }
        if (rem > 14) { STEP(B2); RENORM(); }
    }

    // absolute log-alpha: log(a) + z2*ln2
    const float zln2 = (float)z2 * 0.69314718055994530942f;
#pragma unroll
    for (int i = 0; i < SP; ++i) sal[lane * SP + i] = __logf(a[i]) + zln2;
    __syncthreads();
    if (lane == 0) {
        const float a0 = sal[2 * tl - 1];
        const float a1 = sal[2 * tl];
        const float m  = fmaxf(a0, a1);
        float nll = -(m + __logf(__expf(a0 - m) + __expf(a1 - m)));
        if (!(nll < 1e29f)) nll = 0.f;           // zero_infinity (inf/NaN too)
        out_nll[b] = nll / (float)tl;
    }
}

// ---------------------------------------------------------------------------
// Kernel 3: deterministic mean over B
// ---------------------------------------------------------------------------
__global__ void finalize_kernel(const float* __restrict__ nll, float* __restrict__ out)
{
    if (threadIdx.x == 0 && blockIdx.x == 0) {
        float s = 0.f;
        for (int i = 0; i < B_DIM; ++i) s += nll[i];
        out[0] = s * (1.0f / (float)B_DIM);
    }
}

extern "C" void kernel_launch(void* const* d_in, const int* in_sizes, int n_in,
                              void* d_out, int out_size, void* d_ws, size_t ws_size,
                              hipStream_t stream)
{
    const float* pred     = (const float*)d_in[0];
    const int*   targets  = (const int*)d_in[1];
    const int*   in_lens  = (const int*)d_in[2];
    const int*   tgt_lens = (const int*)d_in[3];
    const float* W        = (const float*)d_in[4];
    const float* bias     = (const float*)d_in[5];

    float* probs = (float*)d_ws;                                  // 32*1000*32 f32 = 4.1 MB
    float* nll   = probs + (size_t)B_DIM * T_DIM * VSTRIDE;       // 32 f32
    float* out   = (float*)d_out;

    head_softmax_kernel<<<(B_DIM * T_DIM) / 32, 256, 0, stream>>>(pred, W, bias, probs);
    ctc_alpha_kernel<<<B_DIM, 64, 0, stream>>>(probs, targets, in_lens, tgt_lens, nll);
    finalize_kernel<<<1, 64, 0, stream>>>(nll, out);
}

// Round 12
// 126.046 us; speedup vs baseline: 1.0926x; 1.0926x over previous
//
#include <hip/hip_runtime.h>
#include <hip/hip_bf16.h>
#include <cstdint>
#include <math.h>

#define B_DIM 32
#define T_DIM 1000
#define D_DIM 768
#define V_DIM 31
#define L_DIM 200
#define S_DIM 401      // 2L+1 CTC states
#define SP 7           // states per lane (64*7 = 448 >= 401)
#define S_PAD 448
#define VSTRIDE 32     // padded prob-row stride: 32 floats = 128 B

typedef __bf16 bf16x8 __attribute__((ext_vector_type(8)));
typedef float  f32x16 __attribute__((ext_vector_type(16)));

#define SB() __builtin_amdgcn_sched_barrier(0)

// Wave-wide shift-up-by-1 via DPP WAVE_SHR1 (0x138): pure VALU. Lane 0 -> 0.
__device__ __forceinline__ float shup1_f(float x) {
    int r = __builtin_amdgcn_update_dpp(0, __float_as_int(x), 0x138, 0xF, 0xF, true);
    return __int_as_float(r);
}
__device__ __forceinline__ int shup1_i(int x) {
    return __builtin_amdgcn_update_dpp(0, x, 0x138, 0xF, 0xF, true);
}

// ---------------------------------------------------------------------------
// Kernel 1: logits = pred @ W^T + b via MFMA bf16, probs = softmax -> ws.
// (Unchanged from round 8: ~29 us.)
// ---------------------------------------------------------------------------
__global__ __launch_bounds__(256) void head_softmax_kernel(
    const float* __restrict__ pred,
    const float* __restrict__ W,
    const float* __restrict__ bias,
    float* __restrict__ probs)
{
    __shared__ float red[3][64][16];   // waves 1..3 partial C tiles (12 KB)
    __shared__ float sm2[32][33];      // transpose pad 33 -> conflict-free
    const int tid  = threadIdx.x;
    const int lane = tid & 63;
    const int w    = __builtin_amdgcn_readfirstlane(tid >> 6);  // K segment
    const int col  = lane & 31;
    const int h    = lane >> 5;
    const int row  = blockIdx.x * 32 + col;     // grid = 1000 exactly
    const int vc   = (col < V_DIM) ? col : (V_DIM - 1);  // clamp pad col

    const float* pA = pred + (size_t)row * D_DIM + w * 192 + 8 * h;
    const float* pB = W + (size_t)vc * D_DIM + w * 192 + 8 * h;

    f32x16 acc;
#pragma unroll
    for (int i = 0; i < 16; ++i) acc[i] = 0.f;

#pragma unroll
    for (int kt = 0; kt < 12; ++kt) {
        const float4 a0 = *reinterpret_cast<const float4*>(pA + kt * 16);
        const float4 a1 = *reinterpret_cast<const float4*>(pA + kt * 16 + 4);
        const float4 b0 = *reinterpret_cast<const float4*>(pB + kt * 16);
        const float4 b1 = *reinterpret_cast<const float4*>(pB + kt * 16 + 4);
        bf16x8 af, bfr;
        af[0] = (__bf16)a0.x; af[1] = (__bf16)a0.y;
        af[2] = (__bf16)a0.z; af[3] = (__bf16)a0.w;
        af[4] = (__bf16)a1.x; af[5] = (__bf16)a1.y;
        af[6] = (__bf16)a1.z; af[7] = (__bf16)a1.w;
        bfr[0] = (__bf16)b0.x; bfr[1] = (__bf16)b0.y;
        bfr[2] = (__bf16)b0.z; bfr[3] = (__bf16)b0.w;
        bfr[4] = (__bf16)b1.x; bfr[5] = (__bf16)b1.y;
        bfr[6] = (__bf16)b1.z; bfr[7] = (__bf16)b1.w;
        acc = __builtin_amdgcn_mfma_f32_32x32x16_bf16(af, bfr, acc, 0, 0, 0);
    }

    if (w > 0) {
#pragma unroll
        for (int q = 0; q < 4; ++q)
            *reinterpret_cast<float4*>(&red[w - 1][lane][q * 4]) =
                make_float4(acc[q * 4], acc[q * 4 + 1], acc[q * 4 + 2], acc[q * 4 + 3]);
    }
    __syncthreads();
    if (w == 0) {
#pragma unroll
        for (int i = 0; i < 16; ++i)
            acc[i] += red[0][lane][i] + red[1][lane][i] + red[2][lane][i];
#pragma unroll
        for (int r = 0; r < 16; ++r) {
            const int rl = (r & 3) + 8 * (r >> 2) + 4 * h;
            sm2[rl][col] = acc[r];
        }
        if (lane < 32) {
            float lg[V_DIM];
            float m = -1e30f;
#pragma unroll
            for (int v = 0; v < V_DIM; ++v) {
                lg[v] = sm2[lane][v] + bias[v];
                m = fmaxf(m, lg[v]);
            }
            float e[32];
            float s = 0.f;
#pragma unroll
            for (int v = 0; v < V_DIM; ++v) { e[v] = __expf(lg[v] - m); s += e[v]; }
            const float inv = 1.0f / s;
#pragma unroll
            for (int v = 0; v < V_DIM; ++v) e[v] *= inv;
            e[31] = 0.f;
            float* op = probs + (size_t)(blockIdx.x * 32 + lane) * VSTRIDE;
#pragma unroll
            for (int q = 0; q < 8; ++q)
                *reinterpret_cast<float4*>(op + q * 4) =
                    *reinterpret_cast<float4*>(&e[q * 4]);
        }
    }
}

// ---------------------------------------------------------------------------
// Kernel 2: CTC forward recursion, linear domain, pow2 renorm every 2 steps.
// DMA staging (3-chunk LDS ring, counted vmcnt) + 4-buffer register rotation
// with sched_barrier(0)-PINNED 2-step read-ahead, and an instruction-dieted
// step/renorm (no gather-address VALU: constant rows fold into ds offsets).
// ---------------------------------------------------------------------------
__global__ __launch_bounds__(64, 1) void ctc_alpha_kernel(
    const float* __restrict__ probs,
    const int* __restrict__ targets,
    const int* __restrict__ in_lens,
    const int* __restrict__ tgt_lens,
    float* __restrict__ out_nll)
{
    __shared__ float lbuf[3][16][VSTRIDE];   // 6 KB ring (3 chunks x 16 rows)
    __shared__ float sal[S_PAD];

    const int b    = blockIdx.x;
    const int lane = threadIdx.x;
    const int Tin  = in_lens[b];
    const int tl   = tgt_lens[b];
    const int* tgt = targets + b * L_DIM;
    const float* __restrict__ prow = probs + (size_t)b * T_DIM * VSTRIDE;

    int   eoff[SP];
    float m2[SP];
#pragma unroll
    for (int i = 0; i < SP; ++i) {
        const int s = lane * SP + i;
        int e = 0;
        float mm = 0.f;
        if (s < S_DIM && (s & 1)) {
            const int k = (s - 1) >> 1;
            const int lab = tgt[k];
            e = lab;
            if (s >= 3 && lab != tgt[k - 1]) mm = 1.f;
        }
        eoff[i] = e;
        m2[i]   = mm;
    }

    // t=0 init
    float a[SP];
#pragma unroll
    for (int i = 0; i < SP; ++i) a[i] = 0.f;
    if (lane == 0) {
        a[0] = prow[0];
        a[1] = prow[eoff[1]];
    }
    int   z2 = 0;
    const float fz = (lane == 0) ? 0.f : 1.0f;   // lane-0 inflow killer
    float f  = fz;

    auto ISSUE = [&](int buf, int tbase) {
#pragma unroll
        for (int i = 0; i < 8; ++i) {
            int rowb = tbase + 2 * i;
            if (rowb > T_DIM - 2) rowb = T_DIM - 2;   // clamp, stays in-bounds
            const float* src = prow + (size_t)rowb * VSTRIDE + lane;
            float* dst = &lbuf[buf][2 * i][0];        // wave-uniform base
            __builtin_amdgcn_global_load_lds(
                (const __attribute__((address_space(1))) void*)src,
                (__attribute__((address_space(3))) void*)dst, 4, 0, 0);
        }
    };

    float B0[SP], B1[SP], B2[SP], B3[SP];
    // row is a compile-time constant at every call site -> row*VSTRIDE folds
    // into the ds_read immediate offset; eoff-based address VGPRs are loop-
    // invariant. Zero per-step address arithmetic.
    auto RD = [&](const float* base, int row, float (&dst)[SP]) {
#pragma unroll
        for (int i = 0; i < SP; ++i) dst[i] = base[row * VSTRIDE + eoff[i]];
    };

    auto STEP = [&](const float (&pp)[SP]) {
        const float a6  = shup1_f(a[SP - 1]);   // DPP: lane0 -> 0
        const float a5  = shup1_f(a[SP - 2]);
        const float am1 = a6 * f;
        const float am2 = a5 * f;
        float nw[SP];
        nw[0] = (a[0] + am1  + m2[0] * am2) * pp[0];
        nw[1] = (a[1] + a[0] + m2[1] * am1) * pp[1];
#pragma unroll
        for (int i = 2; i < SP; ++i)
            nw[i] = (a[i] + a[i - 1] + m2[i] * a[i - 2]) * pp[i];
#pragma unroll
        for (int i = 0; i < SP; ++i) a[i] = nw[i];
    };

    auto RENORM = [&]() {
        const float m01 = fmaxf(fmaxf(a[0], a[1]), a[2]);   // -> v_max3
        const float m34 = fmaxf(fmaxf(a[3], a[4]), a[5]);
        const float mx  = fmaxf(fmaxf(m01, m34), a[6]);
        int e;
        (void)frexpf(mx, &e);                    // mx==0 -> e=0
        const int zc = z2 + e;
        const int zp = shup1_i(zc);              // lane0 -> 0 (never used there)
        z2 = (mx > 0.f) ? zc : zp;               // lane0 mx>0 always (probs>0)
        const int ne = -e;
#pragma unroll
        for (int i = 0; i < SP; ++i) a[i] = ldexpf(a[i], ne);
        int dz = zp - z2;
        dz = (dz > 126) ? 126 : ((dz < -126) ? -126 : dz);  // -> med3
        f = ldexpf(fz, dz);                      // lane0: ldexp(0,..) = 0
    };

    ISSUE(0, 1);            // chunk 0: rows 1..16
    ISSUE(1, 17);           // chunk 1: rows 17..32
    asm volatile("s_waitcnt vmcnt(8)" ::: "memory");  // chunk 0 landed
    {
        const float* Lb = &lbuf[0][0][0];
        RD(Lb, 0, B0);
        RD(Lb, 1, B1);
    }

    int tb = 1;
    int cur = 0;
    while (tb + 16 <= Tin) {
        const float* Lb = &lbuf[cur][0][0];
        const int nx = (cur + 1 == 3) ? 0 : cur + 1;
        const int n2 = (nx + 1 == 3) ? 0 : nx + 1;
        RD(Lb,  2, B2); SB(); STEP(B0);
        RD(Lb,  3, B3); SB(); STEP(B1); RENORM();
        RD(Lb,  4, B0); SB(); STEP(B2);
        RD(Lb,  5, B1); SB(); STEP(B3); RENORM();
        RD(Lb,  6, B2); SB(); STEP(B0);
        RD(Lb,  7, B3); SB(); STEP(B1); RENORM();
        RD(Lb,  8, B0); SB(); STEP(B2);
        RD(Lb,  9, B1); SB(); STEP(B3); RENORM();
        RD(Lb, 10, B2); SB(); STEP(B0);
        RD(Lb, 11, B3); SB(); STEP(B1); RENORM();
        RD(Lb, 12, B0); SB(); STEP(B2);
        RD(Lb, 13, B1); SB(); STEP(B3); RENORM();
        RD(Lb, 14, B2); SB(); STEP(B0);
        RD(Lb, 15, B3); SB(); STEP(B1); RENORM();
        ISSUE(n2, tb + 32);                                // refill oldest buffer
        asm volatile("s_waitcnt vmcnt(8)" ::: "memory");   // next chunk landed
        {
            const float* Ln = &lbuf[nx][0][0];
            RD(Ln, 0, B0); SB(); STEP(B2);                 // step (row 14)
            RD(Ln, 1, B1); SB(); STEP(B3); RENORM();       // step (row 15)
        }
        tb += 16;
        cur = nx;
    }

    // tail: rem <= 15 steps in chunk cur (landed); B0,B1 = rows 0,1
    const int rem = Tin - tb;
    {
        const float* Lb = &lbuf[cur][0][0];
        if (rem >  0) { RD(Lb,  2, B2); STEP(B0); }
        if (rem >  1) { RD(Lb,  3, B3); STEP(B1); RENORM(); }
        if (rem >  2) { RD(Lb,  4, B0); STEP(B2); }
        if (rem >  3) { RD(Lb,  5, B1); STEP(B3); RENORM(); }
        if (rem >  4) { RD(Lb,  6, B2); STEP(B0); }
        if (rem >  5) { RD(Lb,  7, B3); STEP(B1); RENORM(); }
        if (rem >  6) { RD(Lb,  8, B0); STEP(B2); }
        if (rem >  7) { RD(Lb,  9, B1); STEP(B3); RENORM(); }
        if (rem >  8) { RD(Lb, 10, B2); STEP(B0); }
        if (rem >  9) { RD(Lb, 11, B3); STEP(B1); RENORM(); }
        if (rem > 10) { RD(Lb, 12, B0); STEP(B2); }
        if (rem > 11) { RD(Lb, 13, B1); STEP(B3); RENORM(); }
        if (rem > 12) { RD(Lb, 14, B2); STEP(B0); }
        if (rem > 13) { RD(Lb, 15, B3); STEP(B1); RENORM(); }
        if (rem > 14) { STEP(B2); RENORM(); }
    }

    // absolute log-alpha: log(a) + z2*ln2
    const float zln2 = (float)z2 * 0.69314718055994530942f;
#pragma unroll
    for (int i = 0; i < SP; ++i) sal[lane * SP + i] = __logf(a[i]) + zln2;
    __syncthreads();
    if (lane == 0) {
        const float a0 = sal[2 * tl - 1];
        const float a1 = sal[2 * tl];
        const float m  = fmaxf(a0, a1);
        float nll = -(m + __logf(__expf(a0 - m) + __expf(a1 - m)));
        if (!(nll < 1e29f)) nll = 0.f;           // zero_infinity (inf/NaN too)
        out_nll[b] = nll / (float)tl;
    }
}

// ---------------------------------------------------------------------------
// Kernel 3: deterministic mean over B
// ---------------------------------------------------------------------------
__global__ void finalize_kernel(const float* __restrict__ nll, float* __restrict__ out)
{
    if (threadIdx.x == 0 && blockIdx.x == 0) {
        float s = 0.f;
        for (int i = 0; i < B_DIM; ++i) s += nll[i];
        out[0] = s * (1.0f / (float)B_DIM);
    }
}

extern "C" void kernel_launch(void* const* d_in, const int* in_sizes, int n_in,
                              void* d_out, int out_size, void* d_ws, size_t ws_size,
                              hipStream_t stream)
{
    const float* pred     = (const float*)d_in[0];
    const int*   targets  = (const int*)d_in[1];
    const int*   in_lens  = (const int*)d_in[2];
    const int*   tgt_lens = (const int*)d_in[3];
    const float* W        = (const float*)d_in[4];
    const float* bias     = (const float*)d_in[5];

    float* probs = (float*)d_ws;                                  // 32*1000*32 f32 = 4.1 MB
    float* nll   = probs + (size_t)B_DIM * T_DIM * VSTRIDE;       // 32 f32
    float* out   = (float*)d_out;

    head_softmax_kernel<<<(B_DIM * T_DIM) / 32, 256, 0, stream>>>(pred, W, bias, probs);
    ctc_alpha_kernel<<<B_DIM, 64, 0, stream>>>(probs, targets, in_lens, tgt_lens, nll);
    finalize_kernel<<<1, 64, 0, stream>>>(nll, out);
}

// Round 13
// 119.661 us; speedup vs baseline: 1.1509x; 1.0534x over previous
//
#include <hip/hip_runtime.h>
#include <hip/hip_bf16.h>
#include <cstdint>
#include <math.h>

#define B_DIM 32
#define T_DIM 1000
#define D_DIM 768
#define V_DIM 31
#define L_DIM 200
#define S_DIM 401      // 2L+1 CTC states
#define SP 7           // states per lane (64*7 = 448 >= 401)
#define S_PAD 448
#define VSTRIDE 32     // padded prob-row stride: 32 floats = 128 B

typedef __bf16 bf16x8 __attribute__((ext_vector_type(8)));
typedef float  f32x16 __attribute__((ext_vector_type(16)));
typedef __attribute__((address_space(3))) float lds_float;

#define SB() __builtin_amdgcn_sched_barrier(0)

// Wave-wide shift-up-by-1 via DPP WAVE_SHR1 (0x138): pure VALU. Lane 0 -> 0.
__device__ __forceinline__ float shup1_f(float x) {
    int r = __builtin_amdgcn_update_dpp(0, __float_as_int(x), 0x138, 0xF, 0xF, true);
    return __int_as_float(r);
}
__device__ __forceinline__ int shup1_i(int x) {
    return __builtin_amdgcn_update_dpp(0, x, 0x138, 0xF, 0xF, true);
}

// ---------------------------------------------------------------------------
// Kernel 1: logits = pred @ W^T + b via MFMA bf16, probs = softmax -> ws.
// (Unchanged from round 8: ~29 us.)
// ---------------------------------------------------------------------------
__global__ __launch_bounds__(256) void head_softmax_kernel(
    const float* __restrict__ pred,
    const float* __restrict__ W,
    const float* __restrict__ bias,
    float* __restrict__ probs)
{
    __shared__ float red[3][64][16];   // waves 1..3 partial C tiles (12 KB)
    __shared__ float sm2[32][33];      // transpose pad 33 -> conflict-free
    const int tid  = threadIdx.x;
    const int lane = tid & 63;
    const int w    = __builtin_amdgcn_readfirstlane(tid >> 6);  // K segment
    const int col  = lane & 31;
    const int h    = lane >> 5;
    const int row  = blockIdx.x * 32 + col;     // grid = 1000 exactly
    const int vc   = (col < V_DIM) ? col : (V_DIM - 1);  // clamp pad col

    const float* pA = pred + (size_t)row * D_DIM + w * 192 + 8 * h;
    const float* pB = W + (size_t)vc * D_DIM + w * 192 + 8 * h;

    f32x16 acc;
#pragma unroll
    for (int i = 0; i < 16; ++i) acc[i] = 0.f;

#pragma unroll
    for (int kt = 0; kt < 12; ++kt) {
        const float4 a0 = *reinterpret_cast<const float4*>(pA + kt * 16);
        const float4 a1 = *reinterpret_cast<const float4*>(pA + kt * 16 + 4);
        const float4 b0 = *reinterpret_cast<const float4*>(pB + kt * 16);
        const float4 b1 = *reinterpret_cast<const float4*>(pB + kt * 16 + 4);
        bf16x8 af, bfr;
        af[0] = (__bf16)a0.x; af[1] = (__bf16)a0.y;
        af[2] = (__bf16)a0.z; af[3] = (__bf16)a0.w;
        af[4] = (__bf16)a1.x; af[5] = (__bf16)a1.y;
        af[6] = (__bf16)a1.z; af[7] = (__bf16)a1.w;
        bfr[0] = (__bf16)b0.x; bfr[1] = (__bf16)b0.y;
        bfr[2] = (__bf16)b0.z; bfr[3] = (__bf16)b0.w;
        bfr[4] = (__bf16)b1.x; bfr[5] = (__bf16)b1.y;
        bfr[6] = (__bf16)b1.z; bfr[7] = (__bf16)b1.w;
        acc = __builtin_amdgcn_mfma_f32_32x32x16_bf16(af, bfr, acc, 0, 0, 0);
    }

    if (w > 0) {
#pragma unroll
        for (int q = 0; q < 4; ++q)
            *reinterpret_cast<float4*>(&red[w - 1][lane][q * 4]) =
                make_float4(acc[q * 4], acc[q * 4 + 1], acc[q * 4 + 2], acc[q * 4 + 3]);
    }
    __syncthreads();
    if (w == 0) {
#pragma unroll
        for (int i = 0; i < 16; ++i)
            acc[i] += red[0][lane][i] + red[1][lane][i] + red[2][lane][i];
#pragma unroll
        for (int r = 0; r < 16; ++r) {
            const int rl = (r & 3) + 8 * (r >> 2) + 4 * h;
            sm2[rl][col] = acc[r];
        }
        if (lane < 32) {
            float lg[V_DIM];
            float m = -1e30f;
#pragma unroll
            for (int v = 0; v < V_DIM; ++v) {
                lg[v] = sm2[lane][v] + bias[v];
                m = fmaxf(m, lg[v]);
            }
            float e[32];
            float s = 0.f;
#pragma unroll
            for (int v = 0; v < V_DIM; ++v) { e[v] = __expf(lg[v] - m); s += e[v]; }
            const float inv = 1.0f / s;
#pragma unroll
            for (int v = 0; v < V_DIM; ++v) e[v] *= inv;
            e[31] = 0.f;
            float* op = probs + (size_t)(blockIdx.x * 32 + lane) * VSTRIDE;
#pragma unroll
            for (int q = 0; q < 8; ++q)
                *reinterpret_cast<float4*>(op + q * 4) =
                    *reinterpret_cast<float4*>(&e[q * 4]);
        }
    }
}

// --- inline-asm gather: 7 ds_read_b32 with literal row offset ------------
#define DS1(dst, va, off) \
    asm volatile("ds_read_b32 %0, %1 offset:" #off : "=v"(dst) : "v"(va))
#define RD7(B, off) do { \
    DS1(B[0], va[0], off); DS1(B[1], va[1], off); DS1(B[2], va[2], off); \
    DS1(B[3], va[3], off); DS1(B[4], va[4], off); DS1(B[5], va[5], off); \
    DS1(B[6], va[6], off); } while (0)
// counted wait: 14 outstanding = the two just-issued groups; older retired.
#define W14() do { \
    asm volatile("s_waitcnt lgkmcnt(14)" ::: "memory"); \
    __builtin_amdgcn_sched_barrier(0); } while (0)

// ---------------------------------------------------------------------------
// Kernel 2: CTC forward recursion, linear domain, pow2 renorm every 2 steps.
// DMA staging (3-chunk LDS ring, counted vmcnt). LDS gathers + lgkm waits in
// inline asm with COUNTED lgkmcnt(14): 2-group read-ahead, zero per-step
// latency exposure (the compiler's conservative lgkmcnt was the r9-r12 stall).
// ---------------------------------------------------------------------------
__global__ __launch_bounds__(64, 1) void ctc_alpha_kernel(
    const float* __restrict__ probs,
    const int* __restrict__ targets,
    const int* __restrict__ in_lens,
    const int* __restrict__ tgt_lens,
    float* __restrict__ out_nll)
{
    __shared__ float lbuf[3][16][VSTRIDE];   // 6 KB ring (3 chunks x 16 rows)
    __shared__ float sal[S_PAD];

    const int b    = blockIdx.x;
    const int lane = threadIdx.x;
    const int Tin  = in_lens[b];
    const int tl   = tgt_lens[b];
    const int* tgt = targets + b * L_DIM;
    const float* __restrict__ prow = probs + (size_t)b * T_DIM * VSTRIDE;

    int   eoff[SP];
    float m2[SP];
#pragma unroll
    for (int i = 0; i < SP; ++i) {
        const int s = lane * SP + i;
        int e = 0;
        float mm = 0.f;
        if (s < S_DIM && (s & 1)) {
            const int k = (s - 1) >> 1;
            const int lab = tgt[k];
            e = lab;
            if (s >= 3 && lab != tgt[k - 1]) mm = 1.f;
        }
        eoff[i] = e;
        m2[i]   = mm;
    }

    // LDS byte addresses for the asm gathers (loop-invariant VGPRs).
    const uint32_t base = (uint32_t)(uintptr_t)(lds_float*)&lbuf[0][0][0];
    uint32_t va[SP];
#pragma unroll
    for (int i = 0; i < SP; ++i) va[i] = base + (uint32_t)(eoff[i] * 4);

    // t=0 init
    float a[SP];
#pragma unroll
    for (int i = 0; i < SP; ++i) a[i] = 0.f;
    if (lane == 0) {
        a[0] = prow[0];
        a[1] = prow[eoff[1]];
    }
    int   z2 = 0;
    const float fz = (lane == 0) ? 0.f : 1.0f;   // lane-0 inflow killer
    float f  = fz;

    auto ISSUE = [&](int buf, int tbase) {
#pragma unroll
        for (int i = 0; i < 8; ++i) {
            int rowb = tbase + 2 * i;
            if (rowb > T_DIM - 2) rowb = T_DIM - 2;   // clamp, stays in-bounds
            const float* src = prow + (size_t)rowb * VSTRIDE + lane;
            float* dst = &lbuf[buf][2 * i][0];        // wave-uniform base
            __builtin_amdgcn_global_load_lds(
                (const __attribute__((address_space(1))) void*)src,
                (__attribute__((address_space(3))) void*)dst, 4, 0, 0);
        }
    };

    float B0[SP], B1[SP], B2[SP], B3[SP];
    // plain C++ gather (tail only; compiler emits its own waits there)
    auto RDC = [&](const float* bp, int row, float (&dst)[SP]) {
#pragma unroll
        for (int i = 0; i < SP; ++i) dst[i] = bp[row * VSTRIDE + eoff[i]];
    };

    auto STEP = [&](const float (&pp)[SP]) {
        const float a6  = shup1_f(a[SP - 1]);   // DPP: lane0 -> 0
        const float a5  = shup1_f(a[SP - 2]);
        const float am1 = a6 * f;
        const float am2 = a5 * f;
        float nw[SP];
        nw[0] = (a[0] + am1  + m2[0] * am2) * pp[0];
        nw[1] = (a[1] + a[0] + m2[1] * am1) * pp[1];
#pragma unroll
        for (int i = 2; i < SP; ++i)
            nw[i] = (a[i] + a[i - 1] + m2[i] * a[i - 2]) * pp[i];
#pragma unroll
        for (int i = 0; i < SP; ++i) a[i] = nw[i];
    };

    auto RENORM = [&]() {
        const float m01 = fmaxf(fmaxf(a[0], a[1]), a[2]);   // -> v_max3
        const float m34 = fmaxf(fmaxf(a[3], a[4]), a[5]);
        const float mx  = fmaxf(fmaxf(m01, m34), a[6]);
        int e;
        (void)frexpf(mx, &e);                    // mx==0 -> e=0
        const int zc = z2 + e;
        const int zp = shup1_i(zc);              // lane0 -> 0 (never used there)
        z2 = (mx > 0.f) ? zc : zp;               // lane0 mx>0 always (probs>0)
        const int ne = -e;
#pragma unroll
        for (int i = 0; i < SP; ++i) a[i] = ldexpf(a[i], ne);
        int dz = zp - z2;
        dz = (dz > 126) ? 126 : ((dz < -126) ? -126 : dz);  // -> med3
        f = ldexpf(fz, dz);                      // lane0: ldexp(0,..) = 0
    };

    ISSUE(0, 1);            // chunk 0: rows 1..16
    ISSUE(1, 17);           // chunk 1: rows 17..32
    asm volatile("s_waitcnt vmcnt(8)" ::: "memory");  // chunk 0 landed
    RD7(B0, 0);             // row 0 of chunk 0
    RD7(B1, 128);           // row 1 of chunk 0

    int tb = 1;
    int cur = 0;
    while (tb + 16 <= Tin) {
        const int nx = (cur + 1 == 3) ? 0 : cur + 1;
        const int n2 = (nx + 1 == 3) ? 0 : nx + 1;
        // 14 in-chunk steps: read row j+2, wait counted, compute row j
        RD7(B2, 256);  W14(); STEP(B0);
        RD7(B3, 384);  W14(); STEP(B1); RENORM();
        RD7(B0, 512);  W14(); STEP(B2);
        RD7(B1, 640);  W14(); STEP(B3); RENORM();
        RD7(B2, 768);  W14(); STEP(B0);
        RD7(B3, 896);  W14(); STEP(B1); RENORM();
        RD7(B0, 1024); W14(); STEP(B2);
        RD7(B1, 1152); W14(); STEP(B3); RENORM();
        RD7(B2, 1280); W14(); STEP(B0);
        RD7(B3, 1408); W14(); STEP(B1); RENORM();
        RD7(B0, 1536); W14(); STEP(B2);
        RD7(B1, 1664); W14(); STEP(B3); RENORM();
        RD7(B2, 1792); W14(); STEP(B0);
        RD7(B3, 1920); W14(); STEP(B1); RENORM();
        // advance va ring to next chunk (3 VALU x 7, off critical path)
#pragma unroll
        for (int i = 0; i < SP; ++i) {
            uint32_t o = va[i] + 2048u - base;
            if (o >= 6144u) o -= 6144u;
            va[i] = base + o;
        }
        ISSUE(n2, tb + 32);                                // refill oldest
        asm volatile("s_waitcnt vmcnt(8)" ::: "memory");   // next chunk landed
        RD7(B0, 0);    W14(); STEP(B2);                    // row 14
        RD7(B1, 128);  W14(); STEP(B3); RENORM();          // row 15
        tb += 16;
        cur = nx;
    }

    // drain asm reads once; tail (<16 steps) in plain C++
    asm volatile("s_waitcnt lgkmcnt(0)" ::: "memory");
    SB();
    const int rem = Tin - tb;
    {
        const float* Lb = &lbuf[cur][0][0];
        if (rem >  0) { RDC(Lb,  2, B2); STEP(B0); }
        if (rem >  1) { RDC(Lb,  3, B3); STEP(B1); RENORM(); }
        if (rem >  2) { RDC(Lb,  4, B0); STEP(B2); }
        if (rem >  3) { RDC(Lb,  5, B1); STEP(B3); RENORM(); }
        if (rem >  4) { RDC(Lb,  6, B2); STEP(B0); }
        if (rem >  5) { RDC(Lb,  7, B3); STEP(B1); RENORM(); }
        if (rem >  6) { RDC(Lb,  8, B0); STEP(B2); }
        if (rem >  7) { RDC(Lb,  9, B1); STEP(B3); RENORM(); }
        if (rem >  8) { RDC(Lb, 10, B2); STEP(B0); }
        if (rem >  9) { RDC(Lb, 11, B3); STEP(B1); RENORM(); }
        if (rem > 10) { RDC(Lb, 12, B0); STEP(B2); }
        if (rem > 11) { RDC(Lb, 13, B1); STEP(B3); RENORM(); }
        if (rem > 12) { RDC(Lb, 14, B2); STEP(B0); }
        if (rem > 13) { RDC(Lb, 15, B1); STEP(B3); RENORM(); }
        if (rem > 14) { STEP(B2); RENORM(); }
    }

    // absolute log-alpha: log(a) + z2*ln2
    const float zln2 = (float)z2 * 0.69314718055994530942f;
#pragma unroll
    for (int i = 0; i < SP; ++i) sal[lane * SP + i] = __logf(a[i]) + zln2;
    __syncthreads();
    if (lane == 0) {
        const float a0 = sal[2 * tl - 1];
        const float a1 = sal[2 * tl];
        const float m  = fmaxf(a0, a1);
        float nll = -(m + __logf(__expf(a0 - m) + __expf(a1 - m)));
        if (!(nll < 1e29f)) nll = 0.f;           // zero_infinity (inf/NaN too)
        out_nll[b] = nll / (float)tl;
    }
}

// ---------------------------------------------------------------------------
// Kernel 3: deterministic mean over B
// ---------------------------------------------------------------------------
__global__ void finalize_kernel(const float* __restrict__ nll, float* __restrict__ out)
{
    if (threadIdx.x == 0 && blockIdx.x == 0) {
        float s = 0.f;
        for (int i = 0; i < B_DIM; ++i) s += nll[i];
        out[0] = s * (1.0f / (float)B_DIM);
    }
}

extern "C" void kernel_launch(void* const* d_in, const int* in_sizes, int n_in,
                              void* d_out, int out_size, void* d_ws, size_t ws_size,
                              hipStream_t stream)
{
    const float* pred     = (const float*)d_in[0];
    const int*   targets  = (const int*)d_in[1];
    const int*   in_lens  = (const int*)d_in[2];
    const int*   tgt_lens = (const int*)d_in[3];
    const float* W        = (const float*)d_in[4];
    const float* bias     = (const float*)d_in[5];

    float* probs = (float*)d_ws;                                  // 32*1000*32 f32 = 4.1 MB
    float* nll   = probs + (size_t)B_DIM * T_DIM * VSTRIDE;       // 32 f32
    float* out   = (float*)d_out;

    head_softmax_kernel<<<(B_DIM * T_DIM) / 32, 256, 0, stream>>>(pred, W, bias, probs);
    ctc_alpha_kernel<<<B_DIM, 64, 0, stream>>>(probs, targets, in_lens, tgt_lens, nll);
    finalize_kernel<<<1, 64, 0, stream>>>(nll, out);
}

// Round 14
// 113.949 us; speedup vs baseline: 1.2086x; 1.0501x over previous
//
#include <hip/hip_runtime.h>
#include <hip/hip_bf16.h>
#include <cstdint>
#include <math.h>

#define B_DIM 32
#define T_DIM 1000
#define D_DIM 768
#define V_DIM 31
#define L_DIM 200
#define S_DIM 401      // 2L+1 CTC states
#define SP 8           // states per lane (64*8 = 512 >= 401; uniform parity)
#define S_PAD 512
#define VSTRIDE 32     // padded prob-row stride: 32 floats = 128 B

typedef __bf16 bf16x8 __attribute__((ext_vector_type(8)));
typedef float  f32x16 __attribute__((ext_vector_type(16)));
typedef __attribute__((address_space(3))) float lds_float;

#define SB() __builtin_amdgcn_sched_barrier(0)

// Wave-wide shift-up-by-1 via DPP WAVE_SHR1 (0x138): pure VALU. Lane 0 -> 0.
__device__ __forceinline__ float shup1_f(float x) {
    int r = __builtin_amdgcn_update_dpp(0, __float_as_int(x), 0x138, 0xF, 0xF, true);
    return __int_as_float(r);
}
__device__ __forceinline__ int shup1_i(int x) {
    return __builtin_amdgcn_update_dpp(0, x, 0x138, 0xF, 0xF, true);
}

// ---------------------------------------------------------------------------
// Kernel 1: logits = pred @ W^T + b via MFMA bf16, probs = softmax -> ws.
// (Unchanged from round 8: ~29 us.)
// ---------------------------------------------------------------------------
__global__ __launch_bounds__(256) void head_softmax_kernel(
    const float* __restrict__ pred,
    const float* __restrict__ W,
    const float* __restrict__ bias,
    float* __restrict__ probs)
{
    __shared__ float red[3][64][16];   // waves 1..3 partial C tiles (12 KB)
    __shared__ float sm2[32][33];      // transpose pad 33 -> conflict-free
    const int tid  = threadIdx.x;
    const int lane = tid & 63;
    const int w    = __builtin_amdgcn_readfirstlane(tid >> 6);  // K segment
    const int col  = lane & 31;
    const int h    = lane >> 5;
    const int row  = blockIdx.x * 32 + col;     // grid = 1000 exactly
    const int vc   = (col < V_DIM) ? col : (V_DIM - 1);  // clamp pad col

    const float* pA = pred + (size_t)row * D_DIM + w * 192 + 8 * h;
    const float* pB = W + (size_t)vc * D_DIM + w * 192 + 8 * h;

    f32x16 acc;
#pragma unroll
    for (int i = 0; i < 16; ++i) acc[i] = 0.f;

#pragma unroll
    for (int kt = 0; kt < 12; ++kt) {
        const float4 a0 = *reinterpret_cast<const float4*>(pA + kt * 16);
        const float4 a1 = *reinterpret_cast<const float4*>(pA + kt * 16 + 4);
        const float4 b0 = *reinterpret_cast<const float4*>(pB + kt * 16);
        const float4 b1 = *reinterpret_cast<const float4*>(pB + kt * 16 + 4);
        bf16x8 af, bfr;
        af[0] = (__bf16)a0.x; af[1] = (__bf16)a0.y;
        af[2] = (__bf16)a0.z; af[3] = (__bf16)a0.w;
        af[4] = (__bf16)a1.x; af[5] = (__bf16)a1.y;
        af[6] = (__bf16)a1.z; af[7] = (__bf16)a1.w;
        bfr[0] = (__bf16)b0.x; bfr[1] = (__bf16)b0.y;
        bfr[2] = (__bf16)b0.z; bfr[3] = (__bf16)b0.w;
        bfr[4] = (__bf16)b1.x; bfr[5] = (__bf16)b1.y;
        bfr[6] = (__bf16)b1.z; bfr[7] = (__bf16)b1.w;
        acc = __builtin_amdgcn_mfma_f32_32x32x16_bf16(af, bfr, acc, 0, 0, 0);
    }

    if (w > 0) {
#pragma unroll
        for (int q = 0; q < 4; ++q)
            *reinterpret_cast<float4*>(&red[w - 1][lane][q * 4]) =
                make_float4(acc[q * 4], acc[q * 4 + 1], acc[q * 4 + 2], acc[q * 4 + 3]);
    }
    __syncthreads();
    if (w == 0) {
#pragma unroll
        for (int i = 0; i < 16; ++i)
            acc[i] += red[0][lane][i] + red[1][lane][i] + red[2][lane][i];
#pragma unroll
        for (int r = 0; r < 16; ++r) {
            const int rl = (r & 3) + 8 * (r >> 2) + 4 * h;
            sm2[rl][col] = acc[r];
        }
        if (lane < 32) {
            float lg[V_DIM];
            float m = -1e30f;
#pragma unroll
            for (int v = 0; v < V_DIM; ++v) {
                lg[v] = sm2[lane][v] + bias[v];
                m = fmaxf(m, lg[v]);
            }
            float e[32];
            float s = 0.f;
#pragma unroll
            for (int v = 0; v < V_DIM; ++v) { e[v] = __expf(lg[v] - m); s += e[v]; }
            const float inv = 1.0f / s;
#pragma unroll
            for (int v = 0; v < V_DIM; ++v) e[v] *= inv;
            e[31] = 0.f;
            float* op = probs + (size_t)(blockIdx.x * 32 + lane) * VSTRIDE;
#pragma unroll
            for (int q = 0; q < 8; ++q)
                *reinterpret_cast<float4*>(op + q * 4) =
                    *reinterpret_cast<float4*>(&e[q * 4]);
        }
    }
}

// --- inline-asm gather: 4 label reads + 1 blank-broadcast, literal offset --
#define DS1(dst, vaddr, off) \
    asm volatile("ds_read_b32 %0, %1 offset:" #off : "=v"(dst) : "v"(vaddr))
#define RD5(G, off) do { \
    DS1(G[0], va[0], off); DS1(G[1], va[1], off); DS1(G[2], va[2], off); \
    DS1(G[3], va[3], off); DS1(G[4], va[4], off); } while (0)
// counted wait: 10 outstanding = the two just-issued groups; older retired.
#define W10() do { \
    asm volatile("s_waitcnt lgkmcnt(10)" ::: "memory"); \
    __builtin_amdgcn_sched_barrier(0); } while (0)

// ---------------------------------------------------------------------------
// Kernel 2: CTC forward recursion, linear domain, pow2 renorm every 2 steps.
// SP=8: uniform parity -> even states (blank) share ONE broadcast ds_read
// (p0) and need no fma (blank can't skip); only prev-lane a[7] crosses the
// lane boundary (1 DPP). 5 DS/step, counted lgkmcnt(10), DMA-staged ring.
// ---------------------------------------------------------------------------
__global__ __launch_bounds__(64, 1) void ctc_alpha_kernel(
    const float* __restrict__ probs,
    const int* __restrict__ targets,
    const int* __restrict__ in_lens,
    const int* __restrict__ tgt_lens,
    float* __restrict__ out_nll)
{
    __shared__ float lbuf[3][16][VSTRIDE];   // 6 KB ring (3 chunks x 16 rows)
    __shared__ float sal[S_PAD];

    const int b    = blockIdx.x;
    const int lane = threadIdx.x;
    const int Tin  = in_lens[b];
    const int tl   = tgt_lens[b];
    const int* tgt = targets + b * L_DIM;
    const float* __restrict__ prow = probs + (size_t)b * T_DIM * VSTRIDE;

    // Per-lane: 4 odd-state labels (contiguous tgt[4l..4l+3], clamped) + skip
    // masks. Pad states (>=401) are inert: transitions only flow upward in s.
    int   loff[4];
    float m2o[4];
#pragma unroll
    for (int j = 0; j < 4; ++j) {
        int k = 4 * lane + j;
        if (k > L_DIM - 1) k = L_DIM - 1;
        const int lab = tgt[k];
        loff[j] = lab;
        const int s   = 8 * lane + 2 * j + 1;
        const int km1 = (k > 0) ? k - 1 : 0;
        m2o[j] = (s >= 3 && lab != tgt[km1]) ? 1.f : 0.f;
    }

    // LDS byte addresses for the asm gathers (loop-invariant VGPRs).
    const uint32_t base = (uint32_t)(uintptr_t)(lds_float*)&lbuf[0][0][0];
    uint32_t va[5];
#pragma unroll
    for (int j = 0; j < 4; ++j) va[j] = base + (uint32_t)(loff[j] * 4);
    va[4] = base;                              // blank (broadcast) address

    // t=0 init
    float a[SP];
#pragma unroll
    for (int i = 0; i < SP; ++i) a[i] = 0.f;
    if (lane == 0) {
        a[0] = prow[0];
        a[1] = prow[loff[0]];
    }
    int   z2 = 0;
    const float fz = (lane == 0) ? 0.f : 1.0f;   // lane-0 inflow killer
    float f  = fz;

    auto ISSUE = [&](int buf, int tbase) {
#pragma unroll
        for (int i = 0; i < 8; ++i) {
            int rowb = tbase + 2 * i;
            if (rowb > T_DIM - 2) rowb = T_DIM - 2;   // clamp, stays in-bounds
            const float* src = prow + (size_t)rowb * VSTRIDE + lane;
            float* dst = &lbuf[buf][2 * i][0];        // wave-uniform base
            __builtin_amdgcn_global_load_lds(
                (const __attribute__((address_space(1))) void*)src,
                (__attribute__((address_space(3))) void*)dst, 4, 0, 0);
        }
    };

    float GA[5], GB[5], GC[5], GD[5];
    // plain C++ gather (tail only)
    auto RDC = [&](const float* bp, int row, float (&G)[5]) {
#pragma unroll
        for (int j = 0; j < 4; ++j) G[j] = bp[row * VSTRIDE + loff[j]];
        G[4] = bp[row * VSTRIDE];
    };

    // G[0..3] = odd-state label probs, G[4] = blank prob (all lanes equal).
    auto STEP = [&](const float (&G)[5]) {
        const float a7p = shup1_f(a[7]);        // prev-lane state 8l-1
        const float am1 = a7p * f;              // f==0 on lane 0
        float nw[SP];
        nw[0] = (a[0] + am1)                    * G[4];
        nw[1] = (a[1] + a[0] + m2o[0] * am1)    * G[0];
        nw[2] = (a[2] + a[1])                   * G[4];
        nw[3] = (a[3] + a[2] + m2o[1] * a[1])   * G[1];
        nw[4] = (a[4] + a[3])                   * G[4];
        nw[5] = (a[5] + a[4] + m2o[2] * a[3])   * G[2];
        nw[6] = (a[6] + a[5])                   * G[4];
        nw[7] = (a[7] + a[6] + m2o[3] * a[5])   * G[3];
#pragma unroll
        for (int i = 0; i < SP; ++i) a[i] = nw[i];
    };

    auto RENORM = [&]() {
        const float mA = fmaxf(fmaxf(a[0], a[1]), fmaxf(a[2], a[3]));
        const float mB = fmaxf(fmaxf(a[4], a[5]), fmaxf(a[6], a[7]));
        const float mx = fmaxf(mA, mB);
        int e;
        (void)frexpf(mx, &e);                    // mx==0 -> e=0
        const int zc = z2 + e;
        const int zp = shup1_i(zc);              // lane0 -> 0 (never used there)
        z2 = (mx > 0.f) ? zc : zp;               // lane0 mx>0 always (probs>0)
        const int ne = -e;
#pragma unroll
        for (int i = 0; i < SP; ++i) a[i] = ldexpf(a[i], ne);
        int dz = zp - z2;
        dz = (dz > 126) ? 126 : ((dz < -126) ? -126 : dz);  // -> med3
        f = ldexpf(fz, dz);                      // lane0: ldexp(0,..) = 0
    };

    ISSUE(0, 1);            // chunk 0: rows 1..16
    ISSUE(1, 17);           // chunk 1: rows 17..32
    asm volatile("s_waitcnt vmcnt(8)" ::: "memory");  // chunk 0 landed
    RD5(GA, 0);             // row 0 of chunk 0
    RD5(GB, 128);           // row 1 of chunk 0

    int tb = 1;
    int cur = 0;
    while (tb + 16 <= Tin) {
        const int nx = (cur + 1 == 3) ? 0 : cur + 1;
        const int n2 = (nx + 1 == 3) ? 0 : nx + 1;
        // 14 in-chunk steps: read row j+2, wait counted, compute row j
        RD5(GC, 256);  W10(); STEP(GA);
        RD5(GD, 384);  W10(); STEP(GB); RENORM();
        RD5(GA, 512);  W10(); STEP(GC);
        RD5(GB, 640);  W10(); STEP(GD); RENORM();
        RD5(GC, 768);  W10(); STEP(GA);
        RD5(GD, 896);  W10(); STEP(GB); RENORM();
        RD5(GA, 1024); W10(); STEP(GC);
        RD5(GB, 1152); W10(); STEP(GD); RENORM();
        RD5(GC, 1280); W10(); STEP(GA);
        RD5(GD, 1408); W10(); STEP(GB); RENORM();
        RD5(GA, 1536); W10(); STEP(GC);
        RD5(GB, 1664); W10(); STEP(GD); RENORM();
        RD5(GC, 1792); W10(); STEP(GA);
        RD5(GD, 1920); W10(); STEP(GB); RENORM();
        // advance va ring to next chunk (off critical path)
#pragma unroll
        for (int i = 0; i < 5; ++i) {
            uint32_t o = va[i] + 2048u - base;
            if (o >= 6144u) o -= 6144u;
            va[i] = base + o;
        }
        ISSUE(n2, tb + 32);                                // refill oldest
        asm volatile("s_waitcnt vmcnt(8)" ::: "memory");   // next chunk landed
        RD5(GA, 0);    W10(); STEP(GC);                    // row 14
        RD5(GB, 128);  W10(); STEP(GD); RENORM();          // row 15
        tb += 16;
        cur = nx;
    }

    // drain asm reads once; tail (<16 steps) in plain C++
    asm volatile("s_waitcnt lgkmcnt(0)" ::: "memory");
    SB();
    const int rem = Tin - tb;
    {
        const float* Lb = &lbuf[cur][0][0];
        if (rem >  0) { RDC(Lb,  2, GC); STEP(GA); }
        if (rem >  1) { RDC(Lb,  3, GD); STEP(GB); RENORM(); }
        if (rem >  2) { RDC(Lb,  4, GA); STEP(GC); }
        if (rem >  3) { RDC(Lb,  5, GB); STEP(GD); RENORM(); }
        if (rem >  4) { RDC(Lb,  6, GC); STEP(GA); }
        if (rem >  5) { RDC(Lb,  7, GD); STEP(GB); RENORM(); }
        if (rem >  6) { RDC(Lb,  8, GA); STEP(GC); }
        if (rem >  7) { RDC(Lb,  9, GB); STEP(GD); RENORM(); }
        if (rem >  8) { RDC(Lb, 10, GC); STEP(GA); }
        if (rem >  9) { RDC(Lb, 11, GD); STEP(GB); RENORM(); }
        if (rem > 10) { RDC(Lb, 12, GA); STEP(GC); }
        if (rem > 11) { RDC(Lb, 13, GB); STEP(GD); RENORM(); }
        if (rem > 12) { RDC(Lb, 14, GC); STEP(GA); }
        if (rem > 13) { RDC(Lb, 15, GB); STEP(GD); RENORM(); }
        if (rem > 14) { STEP(GC); RENORM(); }
    }

    // absolute log-alpha: log(a) + z2*ln2
    const float zln2 = (float)z2 * 0.69314718055994530942f;
#pragma unroll
    for (int i = 0; i < SP; ++i) sal[lane * SP + i] = __logf(a[i]) + zln2;
    __syncthreads();
    if (lane == 0) {
        const float a0 = sal[2 * tl - 1];
        const float a1 = sal[2 * tl];
        const float m  = fmaxf(a0, a1);
        float nll = -(m + __logf(__expf(a0 - m) + __expf(a1 - m)));
        if (!(nll < 1e29f)) nll = 0.f;           // zero_infinity (inf/NaN too)
        out_nll[b] = nll / (float)tl;
    }
}

// ---------------------------------------------------------------------------
// Kernel 3: deterministic mean over B
// ---------------------------------------------------------------------------
__global__ void finalize_kernel(const float* __restrict__ nll, float* __restrict__ out)
{
    if (threadIdx.x == 0 && blockIdx.x == 0) {
        float s = 0.f;
        for (int i = 0; i < B_DIM; ++i) s += nll[i];
        out[0] = s * (1.0f / (float)B_DIM);
    }
}

extern "C" void kernel_launch(void* const* d_in, const int* in_sizes, int n_in,
                              void* d_out, int out_size, void* d_ws, size_t ws_size,
                              hipStream_t stream)
{
    const float* pred     = (const float*)d_in[0];
    const int*   targets  = (const int*)d_in[1];
    const int*   in_lens  = (const int*)d_in[2];
    const int*   tgt_lens = (const int*)d_in[3];
    const float* W        = (const float*)d_in[4];
    const float* bias     = (const float*)d_in[5];

    float* probs = (float*)d_ws;                                  // 32*1000*32 f32 = 4.1 MB
    float* nll   = probs + (size_t)B_DIM * T_DIM * VSTRIDE;       // 32 f32
    float* out   = (float*)d_out;

    head_softmax_kernel<<<(B_DIM * T_DIM) / 32, 256, 0, stream>>>(pred, W, bias, probs);
    ctc_alpha_kernel<<<B_DIM, 64, 0, stream>>>(probs, targets, in_lens, tgt_lens, nll);
    finalize_kernel<<<1, 64, 0, stream>>>(nll, out);
}